// Round 2
// baseline (1234.293 us; speedup 1.0000x reference)
//
#include <hip/hip_runtime.h>

// Problem constants
#define B_  8192
#define D_  1024
#define H_  4096
#define O_  1024
#define E_  8
#define HG_ 2048
#define MAXT_ 135  // max total row-tiles: 16384/128 + (E_-1)

typedef _Float16 half8 __attribute__((ext_vector_type(8)));
typedef _Float16 half4 __attribute__((ext_vector_type(4)));
typedef float    f32x4 __attribute__((ext_vector_type(4)));

#define MFMA_F16(a, b, c) __builtin_amdgcn_mfma_f32_16x16x32_f16((a), (b), (c), 0, 0, 0)

typedef const unsigned int __attribute__((address_space(1)))* as1_u32;
typedef unsigned int __attribute__((address_space(3)))* as3_u32;

// async global->LDS, 16B per lane. LDS dest = wave-uniform base + lane*16.
__device__ __forceinline__ void gload_lds16(const void* g, void* s) {
  __builtin_amdgcn_global_load_lds((as1_u32)(g), (as3_u32)(s), 16, 0, 0);
}

// Conflict-free chunked tile layout (tile = 128 rows x BK halves, chunk = 16B):
//   chunk(row, kg) = (row>>4)*(16*KG) + kg*16 + (row&15),  KG = BK/8
// Per quarter-wave fragment reads, chunk mod 8 == fr mod 8 -> 2-way (free).

// ---------------------------------------------------------------- small utils
__global__ void zero_small(int* cnt, float* colsum) {
  if (threadIdx.x < E_) { cnt[threadIdx.x] = 0; colsum[threadIdx.x] = 0.f; }
}

// x fp32 -> hi/lo f16 split (row-major; A-operand is K-contig)
__global__ void cvt_x(const float* __restrict__ x, _Float16* __restrict__ xh,
                      _Float16* __restrict__ xl) {
  size_t i = ((size_t)blockIdx.x * 256 + threadIdx.x) * 4;
  float4 v = *(const float4*)(x + i);
  _Float16 h0 = (_Float16)v.x, h1 = (_Float16)v.y, h2 = (_Float16)v.z, h3 = (_Float16)v.w;
  half4 hh = {h0, h1, h2, h3};
  half4 ll = {(_Float16)(v.x - (float)h0), (_Float16)(v.y - (float)h1),
              (_Float16)(v.z - (float)h2), (_Float16)(v.w - (float)h3)};
  *(half4*)(xh + i) = hh;
  *(half4*)(xl + i) = ll;
}

// in: fp32 [M][N] row-major (batched by blockIdx.z). out: f16 [N][M].
template <bool LO>
__global__ void transpose_cvt(const float* __restrict__ in, _Float16* __restrict__ oh,
                              _Float16* __restrict__ ol, int M, int N) {
  __shared__ float t[32][33];
  const size_t boff = (size_t)blockIdx.z * M * N;
  int bx = blockIdx.x * 32, by = blockIdx.y * 32;
  int tx = threadIdx.x, ty = threadIdx.y;
  const float* src = in + boff;
#pragma unroll
  for (int i = ty; i < 32; i += 8) t[i][tx] = src[(size_t)(by + i) * N + bx + tx];
  __syncthreads();
  int tid = ty * 32 + tx;
  int rr = tid >> 3, cq = tid & 7;
  float v0 = t[cq * 4 + 0][rr], v1 = t[cq * 4 + 1][rr];
  float v2 = t[cq * 4 + 2][rr], v3 = t[cq * 4 + 3][rr];
  half4 h = {(_Float16)v0, (_Float16)v1, (_Float16)v2, (_Float16)v3};
  size_t o = boff + (size_t)(bx + rr) * M + by + cq * 4;
  *(half4*)(oh + o) = h;
  if (LO) {
    half4 l = {(_Float16)(v0 - (float)h[0]), (_Float16)(v1 - (float)h[1]),
               (_Float16)(v2 - (float)h[2]), (_Float16)(v3 - (float)h[3])};
    *(half4*)(ol + o) = l;
  }
}

// ------------------------------------------------- gate GEMM (split precision)
// ghid = relu((xh+xl)@(wh+wl)^T + bg1), dropping lo*lo. BK=32, 4 LDS buffers.
__global__ __launch_bounds__(256) void gate_gemm(
    const _Float16* __restrict__ xh, const _Float16* __restrict__ wh,
    const float* __restrict__ bg1, float* __restrict__ ghid) {
  __shared__ _Float16 sAh[128 * 32], sAl[128 * 32], sBh[128 * 32], sBl[128 * 32];
  const int tid = threadIdx.x, wave = tid >> 6;
  const int lane = tid & 63, fr = lane & 15, fq = lane >> 4;
  const int m0 = blockIdx.y * 128, n0 = blockIdx.x * 128;
  const int wm = wave & 1, wn = wave >> 1;
  const size_t XL = (size_t)B_ * D_;   // xl = xh + XL
  const size_t WL = (size_t)HG_ * D_;  // wl = wh + WL

  const _Float16* srcA[2];
  const _Float16* srcB[2];
#pragma unroll
  for (int j = 0; j < 2; j++) {
    int c = j * 256 + tid;
    int g = c >> 6, kg = (c >> 4) & 3, r = c & 15;
    srcA[j] = xh + (size_t)(m0 + g * 16 + r) * D_ + kg * 8;
    srcB[j] = wh + (size_t)(n0 + g * 16 + r) * D_ + kg * 8;
  }
  f32x4 acc[4][4] = {};
  for (int k0 = 0; k0 < D_; k0 += 32) {
    __syncthreads();
#pragma unroll
    for (int j = 0; j < 2; j++) {
      int lb = (j * 256 + wave * 64) * 8;  // halves
      gload_lds16(srcA[j] + k0, sAh + lb);
      gload_lds16(srcA[j] + XL + k0, sAl + lb);
      gload_lds16(srcB[j] + k0, sBh + lb);
      gload_lds16(srcB[j] + WL + k0, sBl + lb);
    }
    __syncthreads();
    half8 ah[4], al[4], bh[4], bl[4];
#pragma unroll
    for (int i = 0; i < 4; i++) {
      int ca = ((wm * 4 + i) * 64 + fq * 16 + fr) * 8;
      int cb = ((wn * 4 + i) * 64 + fq * 16 + fr) * 8;
      ah[i] = *(const half8*)(sAh + ca);
      al[i] = *(const half8*)(sAl + ca);
      bh[i] = *(const half8*)(sBh + cb);
      bl[i] = *(const half8*)(sBl + cb);
    }
#pragma unroll
    for (int mi = 0; mi < 4; mi++)
#pragma unroll
      for (int ni = 0; ni < 4; ni++) {
        acc[mi][ni] = MFMA_F16(ah[mi], bh[ni], acc[mi][ni]);
        acc[mi][ni] = MFMA_F16(ah[mi], bl[ni], acc[mi][ni]);
        acc[mi][ni] = MFMA_F16(al[mi], bh[ni], acc[mi][ni]);
      }
  }
#pragma unroll
  for (int mi = 0; mi < 4; mi++)
#pragma unroll
    for (int i = 0; i < 4; i++) {
      int row = m0 + wm * 64 + mi * 16 + fq * 4 + i;
      float* dst = ghid + (size_t)row * HG_ + n0 + wn * 64;
#pragma unroll
      for (int ni = 0; ni < 4; ni++) {
        int col = ni * 16 + fr;
        dst[col] = fmaxf(acc[mi][ni][i] + bg1[n0 + wn * 64 + col], 0.f);
      }
    }
}

// ------------------------------------------- gate finish: logits/softmax/top2
__global__ __launch_bounds__(256) void gate_finish(
    const float* __restrict__ ghid, const float* __restrict__ wg2,
    const float* __restrict__ bg2, float* __restrict__ gw, int* __restrict__ tok,
    float* __restrict__ tkw, int* __restrict__ tkf, int* __restrict__ cnt,
    float* __restrict__ colsum) {
  __shared__ int s_e[32];
  __shared__ float s_p[32];
  __shared__ float s_col[E_];
  __shared__ int s_c[E_], s_c2[E_], s_b[E_];
  const int tid = threadIdx.x, wave = tid >> 6, lane = tid & 63;
  if (tid < E_) { s_col[tid] = 0.f; s_c[tid] = 0; s_c2[tid] = 0; }
  __syncthreads();
  for (int it = 0; it < 4; it++) {
    int b = blockIdx.x * 16 + wave * 4 + it;
    const float* g = ghid + (size_t)b * HG_;
    float l[8] = {0, 0, 0, 0, 0, 0, 0, 0};
    for (int j = lane; j < HG_; j += 64) {
      float gv = g[j];
      float4 w0 = *(const float4*)(wg2 + (size_t)j * 8);
      float4 w1 = *(const float4*)(wg2 + (size_t)j * 8 + 4);
      l[0] += gv * w0.x; l[1] += gv * w0.y; l[2] += gv * w0.z; l[3] += gv * w0.w;
      l[4] += gv * w1.x; l[5] += gv * w1.y; l[6] += gv * w1.z; l[7] += gv * w1.w;
    }
#pragma unroll
    for (int off = 32; off; off >>= 1)
#pragma unroll
      for (int r = 0; r < 8; r++) l[r] += __shfl_xor(l[r], off);
    if (lane == 0) {
      float w[8];
      float mx = -1e30f;
#pragma unroll
      for (int r = 0; r < 8; r++) { l[r] += bg2[r]; mx = fmaxf(mx, l[r]); }
      float s = 0.f;
#pragma unroll
      for (int r = 0; r < 8; r++) { w[r] = expf(l[r] - mx); s += w[r]; }
      float inv = 1.f / s;
#pragma unroll
      for (int r = 0; r < 8; r++) w[r] *= inv;
      for (int r = 0; r < 8; r++) {
        gw[(size_t)b * 8 + r] = w[r];
        atomicAdd(&s_col[r], w[r]);
      }
      int i1 = 0;
      for (int r = 1; r < 8; r++) if (w[r] > w[i1]) i1 = r;
      int i2 = (i1 == 0) ? 1 : 0;
      for (int r = 0; r < 8; r++) if (r != i1 && w[r] > w[i2]) i2 = r;
      float e2 = expf(w[i2] - w[i1]);
      float p1 = 1.f / (1.f + e2), p2 = e2 / (1.f + e2);
      int sl = (wave * 4 + it) * 2;
      s_e[sl] = i1; s_p[sl] = p1;
      s_e[sl + 1] = i2; s_p[sl + 1] = p2;
    }
  }
  __syncthreads();
  if (tid < 32) atomicAdd(&s_c[s_e[tid]], 1);
  __syncthreads();
  if (tid < E_) s_b[tid] = atomicAdd(&cnt[tid], s_c[tid]);
  __syncthreads();
  if (tid < 32) {
    int e = s_e[tid];
    int slot = s_b[e] + atomicAdd(&s_c2[e], 1);
    int bb = blockIdx.x * 16 + (tid >> 1);
    tok[e * B_ + slot] = bb;
    tkw[e * B_ + slot] = s_p[tid];
    tkf[e * B_ + slot] = tid & 1;
  }
  if (tid < E_) atomicAdd(&colsum[tid], s_col[tid]);
}

// prefix sums + cv loss + dense (expert, row-tile) table
__global__ void prefix_cv(const int* __restrict__ cnt, int* __restrict__ basep,
                          const float* __restrict__ colsum, float* __restrict__ cvout,
                          int* __restrict__ tile_e, int* __restrict__ tile_mt,
                          int* __restrict__ ntiles) {
  if (threadIdx.x == 0) {
    int s = 0, nt = 0;
    for (int e = 0; e < E_; e++) {
      basep[e] = s;
      for (int t = 0; t * 128 < cnt[e]; t++) { tile_e[nt] = e; tile_mt[nt] = t; nt++; }
      s += cnt[e];
    }
    ntiles[0] = nt;
    float cv = 0.f;
    for (int e = 0; e < E_; e++) {
      float f = colsum[e] * (1.f / B_) - 1.f / E_;
      cv += f * f;
    }
    *cvout = cv;
  }
}

// ----------------------------------- expert layer 1: h = relu(x[tok] @ W1[e])
// BK=64, dense tile table. grid (H/128, MAXT_).
__global__ __launch_bounds__(256) void expert_gemm1(
    const _Float16* __restrict__ xh, const _Float16* __restrict__ w1t,
    const float* __restrict__ b1, const int* __restrict__ tok,
    const int* __restrict__ cnt, const int* __restrict__ basep,
    const int* __restrict__ tile_e, const int* __restrict__ tile_mt,
    const int* __restrict__ ntiles, _Float16* __restrict__ hbuf) {
  const int idx = blockIdx.y;
  if (idx >= ntiles[0]) return;
  const int e = tile_e[idx], mt = tile_mt[idx];
  const int ce = cnt[e];
  __shared__ _Float16 sA[128 * 64], sB[128 * 64];
  const int tid = threadIdx.x, wave = tid >> 6;
  const int lane = tid & 63, fr = lane & 15, fq = lane >> 4;
  const int n0 = blockIdx.x * 128;
  const int wm = wave & 1, wn = wave >> 1;
  const _Float16* wte = w1t + (size_t)e * H_ * D_;
  const _Float16* srcA[4];
  const _Float16* srcB[4];
#pragma unroll
  for (int j = 0; j < 4; j++) {
    int c = j * 256 + tid;
    int g = c >> 7, kg = (c >> 4) & 7, r = c & 15;
    int rowA = mt * 128 + g * 16 + r;
    if (rowA > ce - 1) rowA = ce - 1;
    int t = tok[e * B_ + rowA];
    srcA[j] = xh + (size_t)t * D_ + kg * 8;
    srcB[j] = wte + (size_t)(n0 + g * 16 + r) * D_ + kg * 8;
  }
  f32x4 acc[4][4] = {};
  for (int k0 = 0; k0 < D_; k0 += 64) {
    __syncthreads();
#pragma unroll
    for (int j = 0; j < 4; j++) {
      int lb = (j * 256 + wave * 64) * 8;
      gload_lds16(srcA[j] + k0, sA + lb);
      gload_lds16(srcB[j] + k0, sB + lb);
    }
    __syncthreads();
#pragma unroll
    for (int kk = 0; kk < 2; kk++) {
      half8 a[4], b[4];
#pragma unroll
      for (int i = 0; i < 4; i++) {
        a[i] = *(const half8*)(sA + ((wm * 4 + i) * 128 + (kk * 4 + fq) * 16 + fr) * 8);
        b[i] = *(const half8*)(sB + ((wn * 4 + i) * 128 + (kk * 4 + fq) * 16 + fr) * 8);
      }
#pragma unroll
      for (int mi = 0; mi < 4; mi++)
#pragma unroll
        for (int ni = 0; ni < 4; ni++) acc[mi][ni] = MFMA_F16(a[mi], b[ni], acc[mi][ni]);
    }
  }
  const int base = basep[e];
  float bv[4];
#pragma unroll
  for (int ni = 0; ni < 4; ni++) bv[ni] = b1[e * H_ + n0 + wn * 64 + ni * 16 + fr];
#pragma unroll
  for (int mi = 0; mi < 4; mi++)
#pragma unroll
    for (int i = 0; i < 4; i++) {
      int rloc = mt * 128 + wm * 64 + mi * 16 + fq * 4 + i;
      if (rloc < ce) {
        _Float16* dst = hbuf + (size_t)(base + rloc) * H_ + n0 + wn * 64;
#pragma unroll
        for (int ni = 0; ni < 4; ni++)
          dst[ni * 16 + fr] = (_Float16)fmaxf(acc[mi][ni][i] + bv[ni], 0.f);
      }
    }
}

// ------------------------- expert layer 2: obuf[tok,k] = p * (h @ W2[e] + b2)
// BK=64, dense tile table. grid (O/128, MAXT_).
__global__ __launch_bounds__(256) void expert_gemm2(
    const _Float16* __restrict__ hbuf, const _Float16* __restrict__ w2t,
    const float* __restrict__ b2, const int* __restrict__ tok,
    const float* __restrict__ tkw, const int* __restrict__ tkf,
    const int* __restrict__ cnt, const int* __restrict__ basep,
    const int* __restrict__ tile_e, const int* __restrict__ tile_mt,
    const int* __restrict__ ntiles, float* __restrict__ obuf) {
  const int idx = blockIdx.y;
  if (idx >= ntiles[0]) return;
  const int e = tile_e[idx], mt = tile_mt[idx];
  const int ce = cnt[e];
  const int base = basep[e];
  __shared__ _Float16 sA[128 * 64], sB[128 * 64];
  const int tid = threadIdx.x, wave = tid >> 6;
  const int lane = tid & 63, fr = lane & 15, fq = lane >> 4;
  const int n0 = blockIdx.x * 128;
  const int wm = wave & 1, wn = wave >> 1;
  const _Float16* wte = w2t + (size_t)e * O_ * H_;
  const _Float16* srcA[4];
  const _Float16* srcB[4];
#pragma unroll
  for (int j = 0; j < 4; j++) {
    int c = j * 256 + tid;
    int g = c >> 7, kg = (c >> 4) & 7, r = c & 15;
    int rowA = mt * 128 + g * 16 + r;
    if (rowA > ce - 1) rowA = ce - 1;
    srcA[j] = hbuf + (size_t)(base + rowA) * H_ + kg * 8;
    srcB[j] = wte + (size_t)(n0 + g * 16 + r) * H_ + kg * 8;
  }
  f32x4 acc[4][4] = {};
  for (int k0 = 0; k0 < H_; k0 += 64) {
    __syncthreads();
#pragma unroll
    for (int j = 0; j < 4; j++) {
      int lb = (j * 256 + wave * 64) * 8;
      gload_lds16(srcA[j] + k0, sA + lb);
      gload_lds16(srcB[j] + k0, sB + lb);
    }
    __syncthreads();
#pragma unroll
    for (int kk = 0; kk < 2; kk++) {
      half8 a[4], b[4];
#pragma unroll
      for (int i = 0; i < 4; i++) {
        a[i] = *(const half8*)(sA + ((wm * 4 + i) * 128 + (kk * 4 + fq) * 16 + fr) * 8);
        b[i] = *(const half8*)(sB + ((wn * 4 + i) * 128 + (kk * 4 + fq) * 16 + fr) * 8);
      }
#pragma unroll
      for (int mi = 0; mi < 4; mi++)
#pragma unroll
        for (int ni = 0; ni < 4; ni++) acc[mi][ni] = MFMA_F16(a[mi], b[ni], acc[mi][ni]);
    }
  }
  float bv[4];
#pragma unroll
  for (int ni = 0; ni < 4; ni++) bv[ni] = b2[e * O_ + n0 + wn * 64 + ni * 16 + fr];
#pragma unroll
  for (int mi = 0; mi < 4; mi++)
#pragma unroll
    for (int i = 0; i < 4; i++) {
      int rloc = mt * 128 + wm * 64 + mi * 16 + fq * 4 + i;
      if (rloc < ce) {
        int t = tok[e * B_ + rloc];
        float p = tkw[e * B_ + rloc];
        int f = tkf[e * B_ + rloc];
        float* dst = obuf + ((size_t)t * 2 + f) * O_ + n0 + wn * 64;
#pragma unroll
        for (int ni = 0; ni < 4; ni++)
          dst[ni * 16 + fr] = p * (acc[mi][ni][i] + bv[ni]);
      }
    }
}

__global__ void combine(const float* __restrict__ obuf, float* __restrict__ out) {
  size_t i = (size_t)blockIdx.x * 256 + threadIdx.x;
  const float4* o4 = (const float4*)obuf;
  size_t b = i >> 8, c = i & 255;  // O_/4 = 256
  float4 u = o4[(b * 2) * 256 + c];
  float4 v = o4[(b * 2 + 1) * 256 + c];
  float4 w = {u.x + v.x, u.y + v.y, u.z + v.z, u.w + v.w};
  ((float4*)out)[i] = w;
}

// ---------------------------------------------------------------------- host
extern "C" void kernel_launch(void* const* d_in, const int* in_sizes, int n_in,
                              void* d_out, int out_size, void* d_ws, size_t ws_size,
                              hipStream_t stream) {
  const float* x = (const float*)d_in[0];
  const float* W1 = (const float*)d_in[1];
  const float* b1 = (const float*)d_in[2];
  const float* W2 = (const float*)d_in[3];
  const float* b2 = (const float*)d_in[4];
  const float* Wg1 = (const float*)d_in[5];
  const float* bg1 = (const float*)d_in[6];
  const float* Wg2 = (const float*)d_in[7];
  const float* bg2 = (const float*)d_in[8];

  float* out = (float*)d_out;
  float* gw = out + (size_t)B_ * O_;
  float* cv = gw + (size_t)B_ * E_;

  char* w = (char*)d_ws;
  const size_t OFF_XH = 0;
  const size_t OFF_XL = OFF_XH + (size_t)B_ * D_ * 2;
  const size_t OFF_WG1H = OFF_XL + (size_t)B_ * D_ * 2;
  const size_t OFF_WG1L = OFF_WG1H + (size_t)HG_ * D_ * 2;
  const size_t OFF_WT = OFF_WG1L + (size_t)HG_ * D_ * 2;      // W1T then W2T (aliased)
  const size_t OFF_GHID = OFF_WT + (size_t)E_ * H_ * D_ * 2;  // also OBUF (aliased)
  const size_t OFF_HBUF = OFF_GHID + (size_t)B_ * HG_ * 4;
  const size_t OFF_TOK = OFF_HBUF + (size_t)B_ * 2 * H_ * 2;
  const size_t OFF_TKW = OFF_TOK + (size_t)E_ * B_ * 4;
  const size_t OFF_TKF = OFF_TKW + (size_t)E_ * B_ * 4;
  const size_t OFF_CNT = OFF_TKF + (size_t)E_ * B_ * 4;
  const size_t OFF_COL = OFF_CNT + 64;
  const size_t OFF_BASE = OFF_COL + 64;
  const size_t OFF_TE = OFF_BASE + 64;
  const size_t OFF_TM = OFF_TE + 640;
  const size_t OFF_NT = OFF_TM + 640;
  const size_t WS_NEED = OFF_NT + 64;
  if (ws_size < WS_NEED) return;

  _Float16* xh = (_Float16*)(w + OFF_XH);
  _Float16* xl = (_Float16*)(w + OFF_XL);
  _Float16* wg1h = (_Float16*)(w + OFF_WG1H);
  _Float16* wg1l = (_Float16*)(w + OFF_WG1L);
  _Float16* wt = (_Float16*)(w + OFF_WT);
  float* ghid = (float*)(w + OFF_GHID);
  float* obuf = (float*)(w + OFF_GHID);  // alias: ghid dead after gate_finish
  _Float16* hbuf = (_Float16*)(w + OFF_HBUF);
  int* tok = (int*)(w + OFF_TOK);
  float* tkw = (float*)(w + OFF_TKW);
  int* tkf = (int*)(w + OFF_TKF);
  int* cnt = (int*)(w + OFF_CNT);
  float* colsum = (float*)(w + OFF_COL);
  int* basep = (int*)(w + OFF_BASE);
  int* tile_e = (int*)(w + OFF_TE);
  int* tile_mt = (int*)(w + OFF_TM);
  int* ntiles = (int*)(w + OFF_NT);

  zero_small<<<1, 64, 0, stream>>>(cnt, colsum);
  cvt_x<<<(B_ * D_) / (256 * 4), 256, 0, stream>>>(x, xh, xl);
  transpose_cvt<true><<<dim3(HG_ / 32, D_ / 32, 1), dim3(32, 8), 0, stream>>>(
      Wg1, wg1h, wg1l, D_, HG_);
  transpose_cvt<false><<<dim3(H_ / 32, D_ / 32, E_), dim3(32, 8), 0, stream>>>(
      W1, wt, nullptr, D_, H_);
  gate_gemm<<<dim3(HG_ / 128, B_ / 128), 256, 0, stream>>>(xh, wg1h, bg1, ghid);
  gate_finish<<<B_ / 16, 256, 0, stream>>>(ghid, Wg2, bg2, gw, tok, tkw, tkf, cnt, colsum);
  prefix_cv<<<1, 64, 0, stream>>>(cnt, basep, colsum, cv, tile_e, tile_mt, ntiles);
  expert_gemm1<<<dim3(H_ / 128, MAXT_), 256, 0, stream>>>(xh, wt, b1, tok, cnt, basep,
                                                          tile_e, tile_mt, ntiles, hbuf);
  transpose_cvt<false><<<dim3(O_ / 32, H_ / 32, E_), dim3(32, 8), 0, stream>>>(
      W2, wt, nullptr, H_, O_);
  expert_gemm2<<<dim3(O_ / 128, MAXT_), 256, 0, stream>>>(hbuf, wt, b2, tok, tkw, tkf,
                                                          cnt, basep, tile_e, tile_mt,
                                                          ntiles, obuf);
  combine<<<(B_ * O_) / (256 * 4), 256, 0, stream>>>(obuf, out);
}

// Round 3
// 950.732 us; speedup vs baseline: 1.2983x; 1.2983x over previous
//
#include <hip/hip_runtime.h>

// Problem constants
#define B_  8192
#define D_  1024
#define H_  4096
#define O_  1024
#define E_  8
#define HG_ 2048
#define MAXT_ 135  // max total row-tiles: 16384/128 + (E_-1)

typedef _Float16 half8 __attribute__((ext_vector_type(8)));
typedef _Float16 half4 __attribute__((ext_vector_type(4)));
typedef float    f32x4 __attribute__((ext_vector_type(4)));

#define MFMA_F16(a, b, c) __builtin_amdgcn_mfma_f32_16x16x32_f16((a), (b), (c), 0, 0, 0)

typedef const unsigned int __attribute__((address_space(1)))* as1_u32;
typedef unsigned int __attribute__((address_space(3)))* as3_u32;

// async global->LDS, 16B per lane. LDS dest = wave-uniform base + lane*16.
__device__ __forceinline__ void gload_lds16(const void* g, void* s) {
  __builtin_amdgcn_global_load_lds((as1_u32)(g), (as3_u32)(s), 16, 0, 0);
}

// XOR-swizzled tile layout (tile rows x 32 halves, 16B chunks, 4 chunks/row):
//   chunk(row, kg) = row*4 + (kg ^ ((row>>1)&3))
// Staging: lane 4q+j of a wave writes chunk (wave*16+q)*4+j (lane-linear DMA),
// so it must READ global k-chunk j^((q>>1)&3) of row q — same contiguous 64B
// per quad as the unswizzled pattern (coalescing identical to round 1).
// Fragment reads hit chunk mod 8 = 4*(fr&1) + fq^((fr>>1)&3): all 8 bank
// groups exactly twice per quarter-wave -> 2-way, free (m136).

// ---------------------------------------------------------------- small utils
__global__ void zero_small(int* cnt, float* colsum) {
  if (threadIdx.x < E_) { cnt[threadIdx.x] = 0; colsum[threadIdx.x] = 0.f; }
}

// x fp32 -> hi/lo f16 split (row-major; A-operand is K-contig)
__global__ void cvt_x(const float* __restrict__ x, _Float16* __restrict__ xh,
                      _Float16* __restrict__ xl) {
  size_t i = ((size_t)blockIdx.x * 256 + threadIdx.x) * 4;
  float4 v = *(const float4*)(x + i);
  _Float16 h0 = (_Float16)v.x, h1 = (_Float16)v.y, h2 = (_Float16)v.z, h3 = (_Float16)v.w;
  half4 hh = {h0, h1, h2, h3};
  half4 ll = {(_Float16)(v.x - (float)h0), (_Float16)(v.y - (float)h1),
              (_Float16)(v.z - (float)h2), (_Float16)(v.w - (float)h3)};
  *(half4*)(xh + i) = hh;
  *(half4*)(xl + i) = ll;
}

// in: fp32 [M][N] row-major (batched by blockIdx.z). out: f16 [N][M].
template <bool LO>
__global__ void transpose_cvt(const float* __restrict__ in, _Float16* __restrict__ oh,
                              _Float16* __restrict__ ol, int M, int N) {
  __shared__ float t[32][33];
  const size_t boff = (size_t)blockIdx.z * M * N;
  int bx = blockIdx.x * 32, by = blockIdx.y * 32;
  int tx = threadIdx.x, ty = threadIdx.y;
  const float* src = in + boff;
#pragma unroll
  for (int i = ty; i < 32; i += 8) t[i][tx] = src[(size_t)(by + i) * N + bx + tx];
  __syncthreads();
  int tid = ty * 32 + tx;
  int rr = tid >> 3, cq = tid & 7;
  float v0 = t[cq * 4 + 0][rr], v1 = t[cq * 4 + 1][rr];
  float v2 = t[cq * 4 + 2][rr], v3 = t[cq * 4 + 3][rr];
  half4 h = {(_Float16)v0, (_Float16)v1, (_Float16)v2, (_Float16)v3};
  size_t o = boff + (size_t)(bx + rr) * M + by + cq * 4;
  *(half4*)(oh + o) = h;
  if (LO) {
    half4 l = {(_Float16)(v0 - (float)h[0]), (_Float16)(v1 - (float)h[1]),
               (_Float16)(v2 - (float)h[2]), (_Float16)(v3 - (float)h[3])};
    *(half4*)(ol + o) = l;
  }
}

// ------------------------------------------------- gate GEMM (split precision)
// ghid = relu((xh+xl)@(wh+wl)^T + bg1), dropping lo*lo. BK=32.
__global__ __launch_bounds__(256) void gate_gemm(
    const _Float16* __restrict__ xh, const _Float16* __restrict__ xl,
    const _Float16* __restrict__ wh, const _Float16* __restrict__ wl,
    const float* __restrict__ bg1, float* __restrict__ ghid) {
  __shared__ _Float16 sAh[128 * 32], sAl[128 * 32], sBh[128 * 32], sBl[128 * 32];
  const int tid = threadIdx.x, wave = tid >> 6, lane = tid & 63;
  const int fr = lane & 15, fq = lane >> 4;
  const int m0 = blockIdx.y * 128, n0 = blockIdx.x * 128;
  const int q = lane >> 2;
  const int srow = (wave << 4) + q;
  const int scol = (((lane & 3) ^ ((lane >> 3) & 3)) << 3);  // swizzled k-chunk
  const int xsw8 = (fq ^ ((fr >> 1) & 3)) << 3;              // swizzled read off
  _Float16* dA0 = sAh + (wave * 16) * 32;
  _Float16* dA1 = sAh + (64 + wave * 16) * 32;
  _Float16* dA0l = sAl + (wave * 16) * 32;
  _Float16* dA1l = sAl + (64 + wave * 16) * 32;
  _Float16* dB0 = sBh + (wave * 16) * 32;
  _Float16* dB1 = sBh + (64 + wave * 16) * 32;
  _Float16* dB0l = sBl + (wave * 16) * 32;
  _Float16* dB1l = sBl + (64 + wave * 16) * 32;
  const _Float16* gA0 = xh + (size_t)(m0 + srow) * D_ + scol;
  const _Float16* gA1 = xh + (size_t)(m0 + 64 + srow) * D_ + scol;
  const _Float16* gA0l = xl + (size_t)(m0 + srow) * D_ + scol;
  const _Float16* gA1l = xl + (size_t)(m0 + 64 + srow) * D_ + scol;
  const _Float16* gB0 = wh + (size_t)(n0 + srow) * D_ + scol;
  const _Float16* gB1 = wh + (size_t)(n0 + 64 + srow) * D_ + scol;
  const _Float16* gB0l = wl + (size_t)(n0 + srow) * D_ + scol;
  const _Float16* gB1l = wl + (size_t)(n0 + 64 + srow) * D_ + scol;
  f32x4 acc[4][4] = {};
  const int wm = wave & 1, wn = wave >> 1;
  for (int k0 = 0; k0 < D_; k0 += 32) {
    __syncthreads();
    gload_lds16(gA0 + k0, dA0);
    gload_lds16(gA1 + k0, dA1);
    gload_lds16(gA0l + k0, dA0l);
    gload_lds16(gA1l + k0, dA1l);
    gload_lds16(gB0 + k0, dB0);
    gload_lds16(gB1 + k0, dB1);
    gload_lds16(gB0l + k0, dB0l);
    gload_lds16(gB1l + k0, dB1l);
    __syncthreads();
    half8 ah[4], al[4], bh[4], bl[4];
#pragma unroll
    for (int i = 0; i < 4; i++) {
      int ca = (wm * 64 + i * 16 + fr) * 32 + xsw8;
      int cb = (wn * 64 + i * 16 + fr) * 32 + xsw8;
      ah[i] = *(const half8*)(sAh + ca);
      al[i] = *(const half8*)(sAl + ca);
      bh[i] = *(const half8*)(sBh + cb);
      bl[i] = *(const half8*)(sBl + cb);
    }
#pragma unroll
    for (int mi = 0; mi < 4; mi++)
#pragma unroll
      for (int ni = 0; ni < 4; ni++) {
        acc[mi][ni] = MFMA_F16(ah[mi], bh[ni], acc[mi][ni]);
        acc[mi][ni] = MFMA_F16(ah[mi], bl[ni], acc[mi][ni]);
        acc[mi][ni] = MFMA_F16(al[mi], bh[ni], acc[mi][ni]);
      }
  }
#pragma unroll
  for (int mi = 0; mi < 4; mi++)
#pragma unroll
    for (int i = 0; i < 4; i++) {
      int row = m0 + wm * 64 + mi * 16 + fq * 4 + i;
      float* dst = ghid + (size_t)row * HG_ + n0 + wn * 64;
#pragma unroll
      for (int ni = 0; ni < 4; ni++) {
        int col = ni * 16 + fr;
        dst[col] = fmaxf(acc[mi][ni][i] + bg1[n0 + wn * 64 + col], 0.f);
      }
    }
}

// ------------------------------------------- gate finish: logits/softmax/top2
__global__ __launch_bounds__(256) void gate_finish(
    const float* __restrict__ ghid, const float* __restrict__ wg2,
    const float* __restrict__ bg2, float* __restrict__ gw, int* __restrict__ tok,
    float* __restrict__ tkw, int* __restrict__ tkf, int* __restrict__ cnt,
    float* __restrict__ colsum) {
  __shared__ int s_e[32];
  __shared__ float s_p[32];
  __shared__ float s_col[E_];
  __shared__ int s_c[E_], s_c2[E_], s_b[E_];
  const int tid = threadIdx.x, wave = tid >> 6, lane = tid & 63;
  if (tid < E_) { s_col[tid] = 0.f; s_c[tid] = 0; s_c2[tid] = 0; }
  __syncthreads();
  for (int it = 0; it < 4; it++) {
    int b = blockIdx.x * 16 + wave * 4 + it;
    const float* g = ghid + (size_t)b * HG_;
    float l[8] = {0, 0, 0, 0, 0, 0, 0, 0};
    for (int j = lane; j < HG_; j += 64) {
      float gv = g[j];
      float4 w0 = *(const float4*)(wg2 + (size_t)j * 8);
      float4 w1 = *(const float4*)(wg2 + (size_t)j * 8 + 4);
      l[0] += gv * w0.x; l[1] += gv * w0.y; l[2] += gv * w0.z; l[3] += gv * w0.w;
      l[4] += gv * w1.x; l[5] += gv * w1.y; l[6] += gv * w1.z; l[7] += gv * w1.w;
    }
#pragma unroll
    for (int off = 32; off; off >>= 1)
#pragma unroll
      for (int r = 0; r < 8; r++) l[r] += __shfl_xor(l[r], off);
    if (lane == 0) {
      float w[8];
      float mx = -1e30f;
#pragma unroll
      for (int r = 0; r < 8; r++) { l[r] += bg2[r]; mx = fmaxf(mx, l[r]); }
      float s = 0.f;
#pragma unroll
      for (int r = 0; r < 8; r++) { w[r] = expf(l[r] - mx); s += w[r]; }
      float inv = 1.f / s;
#pragma unroll
      for (int r = 0; r < 8; r++) w[r] *= inv;
      for (int r = 0; r < 8; r++) {
        gw[(size_t)b * 8 + r] = w[r];
        atomicAdd(&s_col[r], w[r]);
      }
      int i1 = 0;
      for (int r = 1; r < 8; r++) if (w[r] > w[i1]) i1 = r;
      int i2 = (i1 == 0) ? 1 : 0;
      for (int r = 0; r < 8; r++) if (r != i1 && w[r] > w[i2]) i2 = r;
      float e2 = expf(w[i2] - w[i1]);
      float p1 = 1.f / (1.f + e2), p2 = e2 / (1.f + e2);
      int sl = (wave * 4 + it) * 2;
      s_e[sl] = i1; s_p[sl] = p1;
      s_e[sl + 1] = i2; s_p[sl + 1] = p2;
    }
  }
  __syncthreads();
  if (tid < 32) atomicAdd(&s_c[s_e[tid]], 1);
  __syncthreads();
  if (tid < E_) s_b[tid] = atomicAdd(&cnt[tid], s_c[tid]);
  __syncthreads();
  if (tid < 32) {
    int e = s_e[tid];
    int slot = s_b[e] + atomicAdd(&s_c2[e], 1);
    int bb = blockIdx.x * 16 + (tid >> 1);
    tok[e * B_ + slot] = bb;
    tkw[e * B_ + slot] = s_p[tid];
    tkf[e * B_ + slot] = tid & 1;
  }
  if (tid < E_) atomicAdd(&colsum[tid], s_col[tid]);
}

// prefix sums + cv loss + dense (expert, row-tile) table
__global__ void prefix_cv(const int* __restrict__ cnt, int* __restrict__ basep,
                          const float* __restrict__ colsum, float* __restrict__ cvout,
                          int* __restrict__ tile_e, int* __restrict__ tile_mt,
                          int* __restrict__ ntiles) {
  if (threadIdx.x == 0) {
    int s = 0, nt = 0;
    for (int e = 0; e < E_; e++) {
      basep[e] = s;
      for (int t = 0; t * 128 < cnt[e]; t++) { tile_e[nt] = e; tile_mt[nt] = t; nt++; }
      s += cnt[e];
    }
    ntiles[0] = nt;
    float cv = 0.f;
    for (int e = 0; e < E_; e++) {
      float f = colsum[e] * (1.f / B_) - 1.f / E_;
      cv += f * f;
    }
    *cvout = cv;
  }
}

// ----------------------------------- expert layer 1: h = relu(x[tok] @ W1[e])
// BK=32, dense tile table. grid (H/128, MAXT_).
__global__ __launch_bounds__(256) void expert_gemm1(
    const _Float16* __restrict__ xh, const _Float16* __restrict__ w1t,
    const float* __restrict__ b1, const int* __restrict__ tok,
    const int* __restrict__ cnt, const int* __restrict__ basep,
    const int* __restrict__ tile_e, const int* __restrict__ tile_mt,
    const int* __restrict__ ntiles, _Float16* __restrict__ hbuf) {
  const int idx = blockIdx.y;
  if (idx >= ntiles[0]) return;
  const int e = tile_e[idx], mt = tile_mt[idx];
  const int ce = cnt[e];
  __shared__ _Float16 sA[128 * 32], sB[128 * 32];
  const int tid = threadIdx.x, wave = tid >> 6, lane = tid & 63;
  const int fr = lane & 15, fq = lane >> 4;
  const int n0 = blockIdx.x * 128;
  const int q = lane >> 2;
  const int srow = (wave << 4) + q;
  const int scol = (((lane & 3) ^ ((lane >> 3) & 3)) << 3);
  const int xsw8 = (fq ^ ((fr >> 1) & 3)) << 3;
  int r0 = mt * 128 + srow, r1 = r0 + 64;
  if (r0 > ce - 1) r0 = ce - 1;
  if (r1 > ce - 1) r1 = ce - 1;
  const int t0 = tok[e * B_ + r0], t1 = tok[e * B_ + r1];
  const _Float16* gA0 = xh + (size_t)t0 * D_ + scol;
  const _Float16* gA1 = xh + (size_t)t1 * D_ + scol;
  const _Float16* wte = w1t + (size_t)e * H_ * D_;
  const _Float16* gB0 = wte + (size_t)(n0 + srow) * D_ + scol;
  const _Float16* gB1 = wte + (size_t)(n0 + 64 + srow) * D_ + scol;
  _Float16* dA0 = sA + (wave * 16) * 32;
  _Float16* dA1 = sA + (64 + wave * 16) * 32;
  _Float16* dB0 = sB + (wave * 16) * 32;
  _Float16* dB1 = sB + (64 + wave * 16) * 32;
  f32x4 acc[4][4] = {};
  const int wm = wave & 1, wn = wave >> 1;
  for (int k0 = 0; k0 < D_; k0 += 32) {
    __syncthreads();
    gload_lds16(gA0 + k0, dA0);
    gload_lds16(gA1 + k0, dA1);
    gload_lds16(gB0 + k0, dB0);
    gload_lds16(gB1 + k0, dB1);
    __syncthreads();
    half8 a[4], b[4];
#pragma unroll
    for (int i = 0; i < 4; i++) {
      a[i] = *(const half8*)(sA + (wm * 64 + i * 16 + fr) * 32 + xsw8);
      b[i] = *(const half8*)(sB + (wn * 64 + i * 16 + fr) * 32 + xsw8);
    }
#pragma unroll
    for (int mi = 0; mi < 4; mi++)
#pragma unroll
      for (int ni = 0; ni < 4; ni++) acc[mi][ni] = MFMA_F16(a[mi], b[ni], acc[mi][ni]);
  }
  const int base = basep[e];
  float bv[4];
#pragma unroll
  for (int ni = 0; ni < 4; ni++) bv[ni] = b1[e * H_ + n0 + wn * 64 + ni * 16 + fr];
#pragma unroll
  for (int mi = 0; mi < 4; mi++)
#pragma unroll
    for (int i = 0; i < 4; i++) {
      int rloc = mt * 128 + wm * 64 + mi * 16 + fq * 4 + i;
      if (rloc < ce) {
        _Float16* dst = hbuf + (size_t)(base + rloc) * H_ + n0 + wn * 64;
#pragma unroll
        for (int ni = 0; ni < 4; ni++)
          dst[ni * 16 + fr] = (_Float16)fmaxf(acc[mi][ni][i] + bv[ni], 0.f);
      }
    }
}

// ------------- expert layer 2: obuf[tok,f,ks] = p * (h @ W2[e])  (2-way K-split)
// BK=32, dense tile table. grid (O/128, MAXT_, 2). f16 output slices.
__global__ __launch_bounds__(256) void expert_gemm2(
    const _Float16* __restrict__ hbuf, const _Float16* __restrict__ w2t,
    const float* __restrict__ b2, const int* __restrict__ tok,
    const float* __restrict__ tkw, const int* __restrict__ tkf,
    const int* __restrict__ cnt, const int* __restrict__ basep,
    const int* __restrict__ tile_e, const int* __restrict__ tile_mt,
    const int* __restrict__ ntiles, _Float16* __restrict__ obuf) {
  const int idx = blockIdx.y;
  if (idx >= ntiles[0]) return;
  const int e = tile_e[idx], mt = tile_mt[idx];
  const int ks = blockIdx.z;
  const int ce = cnt[e];
  const int base = basep[e];
  __shared__ _Float16 sA[128 * 32], sB[128 * 32];
  const int tid = threadIdx.x, wave = tid >> 6, lane = tid & 63;
  const int fr = lane & 15, fq = lane >> 4;
  const int n0 = blockIdx.x * 128;
  const int q = lane >> 2;
  const int srow = (wave << 4) + q;
  const int scol = (((lane & 3) ^ ((lane >> 3) & 3)) << 3);
  const int xsw8 = (fq ^ ((fr >> 1) & 3)) << 3;
  int r0 = mt * 128 + srow, r1 = r0 + 64;
  if (r0 > ce - 1) r0 = ce - 1;
  if (r1 > ce - 1) r1 = ce - 1;
  const _Float16* gA0 = hbuf + (size_t)(base + r0) * H_ + scol;
  const _Float16* gA1 = hbuf + (size_t)(base + r1) * H_ + scol;
  const _Float16* wte = w2t + (size_t)e * O_ * H_;
  const _Float16* gB0 = wte + (size_t)(n0 + srow) * H_ + scol;
  const _Float16* gB1 = wte + (size_t)(n0 + 64 + srow) * H_ + scol;
  _Float16* dA0 = sA + (wave * 16) * 32;
  _Float16* dA1 = sA + (64 + wave * 16) * 32;
  _Float16* dB0 = sB + (wave * 16) * 32;
  _Float16* dB1 = sB + (64 + wave * 16) * 32;
  f32x4 acc[4][4] = {};
  const int wm = wave & 1, wn = wave >> 1;
  const int kbeg = ks * (H_ / 2), kend = kbeg + H_ / 2;
  for (int k0 = kbeg; k0 < kend; k0 += 32) {
    __syncthreads();
    gload_lds16(gA0 + k0, dA0);
    gload_lds16(gA1 + k0, dA1);
    gload_lds16(gB0 + k0, dB0);
    gload_lds16(gB1 + k0, dB1);
    __syncthreads();
    half8 a[4], b[4];
#pragma unroll
    for (int i = 0; i < 4; i++) {
      a[i] = *(const half8*)(sA + (wm * 64 + i * 16 + fr) * 32 + xsw8);
      b[i] = *(const half8*)(sB + (wn * 64 + i * 16 + fr) * 32 + xsw8);
    }
#pragma unroll
    for (int mi = 0; mi < 4; mi++)
#pragma unroll
      for (int ni = 0; ni < 4; ni++) acc[mi][ni] = MFMA_F16(a[mi], b[ni], acc[mi][ni]);
  }
  float bv[4] = {0.f, 0.f, 0.f, 0.f};
  if (ks == 0) {
#pragma unroll
    for (int ni = 0; ni < 4; ni++) bv[ni] = b2[e * O_ + n0 + wn * 64 + ni * 16 + fr];
  }
#pragma unroll
  for (int mi = 0; mi < 4; mi++)
#pragma unroll
    for (int i = 0; i < 4; i++) {
      int rloc = mt * 128 + wm * 64 + mi * 16 + fq * 4 + i;
      if (rloc < ce) {
        int t = tok[e * B_ + rloc];
        float p = tkw[e * B_ + rloc];
        int f = tkf[e * B_ + rloc];
        _Float16* dst = obuf + ((size_t)t * 4 + f * 2 + ks) * O_ + n0 + wn * 64;
#pragma unroll
        for (int ni = 0; ni < 4; ni++)
          dst[ni * 16 + fr] = (_Float16)(p * (acc[mi][ni][i] + bv[ni]));
      }
    }
}

// sum the 4 f16 slices per token -> fp32 out
__global__ void combine(const _Float16* __restrict__ obuf, float* __restrict__ out) {
  size_t i = (size_t)blockIdx.x * 256 + threadIdx.x;  // half4 group, B_*O_/4 total
  size_t t = i >> 8, c = (i & 255) * 4;               // O_/4 = 256
  const _Float16* base = obuf + (size_t)t * 4 * O_ + c;
  float4 r = {0.f, 0.f, 0.f, 0.f};
#pragma unroll
  for (int s = 0; s < 4; s++) {
    half4 v = *(const half4*)(base + (size_t)s * O_);
    r.x += (float)v[0]; r.y += (float)v[1]; r.z += (float)v[2]; r.w += (float)v[3];
  }
  ((float4*)out)[i] = r;
}

// ---------------------------------------------------------------------- host
extern "C" void kernel_launch(void* const* d_in, const int* in_sizes, int n_in,
                              void* d_out, int out_size, void* d_ws, size_t ws_size,
                              hipStream_t stream) {
  const float* x = (const float*)d_in[0];
  const float* W1 = (const float*)d_in[1];
  const float* b1 = (const float*)d_in[2];
  const float* W2 = (const float*)d_in[3];
  const float* b2 = (const float*)d_in[4];
  const float* Wg1 = (const float*)d_in[5];
  const float* bg1 = (const float*)d_in[6];
  const float* Wg2 = (const float*)d_in[7];
  const float* bg2 = (const float*)d_in[8];

  float* out = (float*)d_out;
  float* gw = out + (size_t)B_ * O_;
  float* cv = gw + (size_t)B_ * E_;

  char* w = (char*)d_ws;
  const size_t OFF_XH = 0;
  const size_t OFF_XL = OFF_XH + (size_t)B_ * D_ * 2;
  const size_t OFF_WG1H = OFF_XL + (size_t)B_ * D_ * 2;
  const size_t OFF_WG1L = OFF_WG1H + (size_t)HG_ * D_ * 2;
  const size_t OFF_WT = OFF_WG1L + (size_t)HG_ * D_ * 2;      // W1T then W2T (aliased)
  const size_t OFF_GHID = OFF_WT + (size_t)E_ * H_ * D_ * 2;  // fp32 ghid; f16 obuf alias
  const size_t OFF_HBUF = OFF_GHID + (size_t)B_ * HG_ * 4;
  const size_t OFF_TOK = OFF_HBUF + (size_t)B_ * 2 * H_ * 2;
  const size_t OFF_TKW = OFF_TOK + (size_t)E_ * B_ * 4;
  const size_t OFF_TKF = OFF_TKW + (size_t)E_ * B_ * 4;
  const size_t OFF_CNT = OFF_TKF + (size_t)E_ * B_ * 4;
  const size_t OFF_COL = OFF_CNT + 64;
  const size_t OFF_BASE = OFF_COL + 64;
  const size_t OFF_TE = OFF_BASE + 64;
  const size_t OFF_TM = OFF_TE + 640;
  const size_t OFF_NT = OFF_TM + 640;
  const size_t WS_NEED = OFF_NT + 64;
  if (ws_size < WS_NEED) return;

  _Float16* xh = (_Float16*)(w + OFF_XH);
  _Float16* xl = (_Float16*)(w + OFF_XL);
  _Float16* wg1h = (_Float16*)(w + OFF_WG1H);
  _Float16* wg1l = (_Float16*)(w + OFF_WG1L);
  _Float16* wt = (_Float16*)(w + OFF_WT);
  float* ghid = (float*)(w + OFF_GHID);
  _Float16* obuf = (_Float16*)(w + OFF_GHID);  // f16 [B][2 slot][2 ks][O], 64 MB: fits
  _Float16* hbuf = (_Float16*)(w + OFF_HBUF);
  int* tok = (int*)(w + OFF_TOK);
  float* tkw = (float*)(w + OFF_TKW);
  int* tkf = (int*)(w + OFF_TKF);
  int* cnt = (int*)(w + OFF_CNT);
  float* colsum = (float*)(w + OFF_COL);
  int* basep = (int*)(w + OFF_BASE);
  int* tile_e = (int*)(w + OFF_TE);
  int* tile_mt = (int*)(w + OFF_TM);
  int* ntiles = (int*)(w + OFF_NT);

  zero_small<<<1, 64, 0, stream>>>(cnt, colsum);
  cvt_x<<<(B_ * D_) / (256 * 4), 256, 0, stream>>>(x, xh, xl);
  transpose_cvt<true><<<dim3(HG_ / 32, D_ / 32, 1), dim3(32, 8), 0, stream>>>(
      Wg1, wg1h, wg1l, D_, HG_);
  transpose_cvt<false><<<dim3(H_ / 32, D_ / 32, E_), dim3(32, 8), 0, stream>>>(
      W1, wt, nullptr, D_, H_);
  gate_gemm<<<dim3(HG_ / 128, B_ / 128), 256, 0, stream>>>(xh, xl, wg1h, wg1l, bg1, ghid);
  gate_finish<<<B_ / 16, 256, 0, stream>>>(ghid, Wg2, bg2, gw, tok, tkw, tkf, cnt, colsum);
  prefix_cv<<<1, 64, 0, stream>>>(cnt, basep, colsum, cv, tile_e, tile_mt, ntiles);
  expert_gemm1<<<dim3(H_ / 128, MAXT_), 256, 0, stream>>>(xh, wt, b1, tok, cnt, basep,
                                                          tile_e, tile_mt, ntiles, hbuf);
  transpose_cvt<false><<<dim3(O_ / 32, H_ / 32, E_), dim3(32, 8), 0, stream>>>(
      W2, wt, nullptr, H_, O_);
  expert_gemm2<<<dim3(O_ / 128, MAXT_, 2), 256, 0, stream>>>(hbuf, wt, b2, tok, tkw, tkf,
                                                             cnt, basep, tile_e, tile_mt,
                                                             ntiles, obuf);
  combine<<<(B_ * O_) / (256 * 4), 256, 0, stream>>>(obuf, out);
}